// Round 1
// baseline (68.849 us; speedup 1.0000x reference)
//
#include <hip/hip_runtime.h>

// GraphConv: out[b,i,c] = relu( VW[b,0,i,c] + sum_{j,l} A[b,i,j,l] * VW[b,l+1,j,c] )
// VW[b,l,j,c] = sum_f V[b,j,f] h[l,c,f]
// K2 key fact: flattening A's (j,l) axes gives contiguous K=4096 with k=j*4+l.

typedef float          f32x4  __attribute__((ext_vector_type(4)));
typedef __bf16         bf16x8 __attribute__((ext_vector_type(8)));
typedef unsigned short u16x4  __attribute__((ext_vector_type(4)));
typedef unsigned int   u32x4  __attribute__((ext_vector_type(4)));

#define DEV __device__ __forceinline__

DEV void glds16(const void* g, void* l) {
  __builtin_amdgcn_global_load_lds((const __attribute__((address_space(1))) void*)g,
                                   (__attribute__((address_space(3))) void*)l,
                                   16, 0, 0);
}

DEV void cvt8(__bf16* d, f32x4 u, f32x4 v) {
  bf16x8 o;
  o[0]=(__bf16)u[0]; o[1]=(__bf16)u[1]; o[2]=(__bf16)u[2]; o[3]=(__bf16)u[3];
  o[4]=(__bf16)v[0]; o[5]=(__bf16)v[1]; o[6]=(__bf16)v[2]; o[7]=(__bf16)v[3];
  *(bf16x8*)d = o;
}

DEV unsigned short bfbits(float x) {
  return __builtin_bit_cast(unsigned short, (__bf16)x);
}

// ---------------------------------------------------------------------------
// K1: VW projection.  Per block: (b, j-tile 128, c-tile 64), all 5 l.
// M-axis = c (16-dim rows), N-axis = j, K = f (256, 4 steps of 64).
// Writes W2t[b][c][j*4 + (l-1)] bf16 (packed 4xl per store) and VW0[b][j][c] f32.
// LDS bf16 tiles [rows][64k], 8 chunks of 16B per row, XOR swizzle q ^= (row&7).
// ---------------------------------------------------------------------------
__global__ __launch_bounds__(512, 2)
void k1_vw(const float* __restrict__ Vg, const float* __restrict__ Hg,
           unsigned short* __restrict__ W2t, float* __restrict__ VW0)
{
  __shared__ __attribute__((aligned(16))) __bf16 Vs[2][128*64];  // 2 x 16 KB
  __shared__ __attribute__((aligned(16))) __bf16 Hs[2][320*64];  // 2 x 40 KB

  const int tid  = threadIdx.x;
  const int lane = tid & 63;
  const int wid  = tid >> 6;   // 0..7
  const int wj   = wid >> 1;   // 0..3 (j strips of 32)
  const int wc   = wid & 1;    // 0..1 (c strips of 32)
  const int li   = lane & 15;
  const int lg   = lane >> 4;

  const int bid = blockIdx.x;
  const int ct  = bid & 3;
  const int jt  = (bid >> 2) & 7;
  const int b   = bid >> 5;
  const int j0  = jt * 128;
  const int c0  = ct * 64;

  // staging: 7 chunks/thread (2 V + 5 H), chunk = 16B bf16 <- 32B f32
  const float* sptr[7];
  int sdst[7];
#pragma unroll
  for (int r = 0; r < 2; ++r) {
    int n = r*512 + tid, row = n >> 3, q = n & 7;
    sptr[r] = Vg + (size_t)(b*1024 + j0 + row)*256 + q*8;
    sdst[r] = row*64 + ((q ^ (row & 7))*8);
  }
#pragma unroll
  for (int r = 0; r < 5; ++r) {
    int n = r*512 + tid, row = n >> 3, q = n & 7;
    int l = row >> 6, cl = row & 63;
    sptr[2+r] = Hg + (size_t)(l*256 + c0 + cl)*256 + q*8;
    sdst[2+r] = row*64 + ((q ^ (row & 7))*8);
  }

  f32x4 acc[5][2][2];
#pragma unroll
  for (int l=0;l<5;l++)
#pragma unroll
    for (int x=0;x<2;x++)
#pragma unroll
      for (int y=0;y<2;y++) acc[l][x][y] = (f32x4){0.f,0.f,0.f,0.f};

  // prologue: stage K-tile 0
  {
    f32x4 sa[14];
#pragma unroll
    for (int i=0;i<7;i++) { sa[2*i] = *(const f32x4*)(sptr[i]); sa[2*i+1] = *(const f32x4*)(sptr[i]+4); }
#pragma unroll
    for (int i=0;i<7;i++) {
      __bf16* d = (i < 2) ? &Vs[0][sdst[i]] : &Hs[0][sdst[i]];
      cvt8(d, sa[2*i], sa[2*i+1]);
    }
  }
  __syncthreads();

  int cur = 0;
#pragma unroll 1
  for (int t = 0; t < 4; ++t) {
    const int nxt = cur ^ 1;
    f32x4 sa[14];
    if (t < 3) {
      const int ko = (t+1)*64;
#pragma unroll
      for (int i=0;i<7;i++) { sa[2*i] = *(const f32x4*)(sptr[i]+ko); sa[2*i+1] = *(const f32x4*)(sptr[i]+ko+4); }
    }
    const __bf16* Vsc = &Vs[cur][0];
    const __bf16* Hsc = &Hs[cur][0];
#pragma unroll
    for (int ks = 0; ks < 2; ++ks) {
      bf16x8 hf[10], vf[2];
#pragma unroll
      for (int l=0;l<5;l++)
#pragma unroll
        for (int cm=0;cm<2;cm++) {
          int row = l*64 + wc*32 + cm*16 + li;
          int ch  = (ks*4 + lg) ^ (row & 7);
          hf[l*2+cm] = *(const bf16x8*)(Hsc + row*64 + ch*8);
        }
#pragma unroll
      for (int jn=0;jn<2;jn++) {
        int row = wj*32 + jn*16 + li;
        int ch  = (ks*4 + lg) ^ (row & 7);
        vf[jn] = *(const bf16x8*)(Vsc + row*64 + ch*8);
      }
#pragma unroll
      for (int l=0;l<5;l++)
#pragma unroll
        for (int cm=0;cm<2;cm++)
#pragma unroll
          for (int jn=0;jn<2;jn++)
            acc[l][cm][jn] = __builtin_amdgcn_mfma_f32_16x16x32_bf16(
                hf[l*2+cm], vf[jn], acc[l][cm][jn], 0, 0, 0);
    }
    if (t < 3) {
#pragma unroll
      for (int i=0;i<7;i++) {
        __bf16* d = (i < 2) ? &Vs[nxt][sdst[i]] : &Hs[nxt][sdst[i]];
        cvt8(d, sa[2*i], sa[2*i+1]);
      }
    }
    __syncthreads();
    cur = nxt;
  }

  // epilogue: D[row=c][col=j]; pack l=1..4 into W2t, l=0 -> VW0 f32
#pragma unroll
  for (int cm=0;cm<2;cm++)
#pragma unroll
    for (int r=0;r<4;r++) {
      const int c = c0 + wc*32 + cm*16 + lg*4 + r;
#pragma unroll
      for (int jn=0;jn<2;jn++) {
        const int j = j0 + wj*32 + jn*16 + li;
        u16x4 pk;
        pk[0] = bfbits(acc[1][cm][jn][r]);
        pk[1] = bfbits(acc[2][cm][jn][r]);
        pk[2] = bfbits(acc[3][cm][jn][r]);
        pk[3] = bfbits(acc[4][cm][jn][r]);
        *(u16x4*)(W2t + (size_t)(b*256 + c)*4096 + (size_t)j*4) = pk;
        VW0[(size_t)(b*1024 + j)*256 + c] = acc[0][cm][jn][r];
      }
    }
}

// ---------------------------------------------------------------------------
// K2: partial[kt][b][i][c] = sum_{k in chunk} A[b][i][k] * W2t[b][c][k]
// tile 128x128, K-chunk 1024 (k-split 4), grid 512 = 2 blocks/CU.
// 4 waves (2x2), wave 64x64 = 4x4 frags, K-step 32, double-buffered LDS.
// A: reg-stage f32->bf16 (issue-early/write-late); B: global_load_lds with
// pre-swizzled source. LDS tiles [128][32] bf16, 4 chunks/row, q ^= (row>>1)&3.
// ---------------------------------------------------------------------------
__global__ __launch_bounds__(256, 2)
void k2_gemm(const float* __restrict__ Ag, const unsigned short* __restrict__ W2t,
             unsigned short* __restrict__ part)
{
  __shared__ __attribute__((aligned(16))) __bf16 As[2][128*32];  // 2 x 8 KB
  __shared__ __attribute__((aligned(16))) __bf16 Bs[2][128*32];  // 2 x 8 KB

  const int tid  = threadIdx.x;
  const int lane = tid & 63;
  const int wid  = tid >> 6;   // 0..3
  const int wi   = wid >> 1;   // 0..1
  const int wc   = wid & 1;    // 0..1
  const int li   = lane & 15;
  const int lg   = lane >> 4;

  const int bid = blockIdx.x;
  const int ct  = bid & 1;
  const int kt  = (bid >> 1) & 3;
  const int it  = (bid >> 3) & 7;
  const int b   = bid >> 6;

  const int i0 = it*128, c0 = ct*128;
  const int k0 = kt*1024;

  // A staging: 2 chunks/thread (chunk n: row=n>>2, q=n&3)
  const int ar0 = tid >> 2,        aq0 = tid & 3;
  const int ar1 = (256+tid) >> 2,  aq1 = (256+tid) & 3;
  const float* ap0 = Ag + (size_t)(b*1024 + i0 + ar0)*4096 + k0 + aq0*8;
  const float* ap1 = Ag + (size_t)(b*1024 + i0 + ar1)*4096 + k0 + aq1*8;
  const int ad0 = ar0*32 + ((aq0 ^ ((ar0 >> 1) & 3))*8);
  const int ad1 = ar1*32 + ((aq1 ^ ((ar1 >> 1) & 3))*8);

  // B staging via glds (2 rounds/thread), source pre-swizzled
  const int bn0 = wid*64 + lane,  br0 = bn0 >> 2, bq0 = bn0 & 3;
  const int bn1 = 256 + bn0,      br1 = bn1 >> 2, bq1 = bn1 & 3;
  const unsigned short* bp0 = W2t + (size_t)(b*256 + c0 + br0)*4096 + k0 + ((bq0 ^ ((br0 >> 1) & 3))*8);
  const unsigned short* bp1 = W2t + (size_t)(b*256 + c0 + br1)*4096 + k0 + ((bq1 ^ ((br1 >> 1) & 3))*8);
  const int bd0 = wid*512;         // element offset; HW adds lane*16B
  const int bd1 = 2048 + wid*512;

  f32x4 acc[4][4];
#pragma unroll
  for (int m=0;m<4;m++)
#pragma unroll
    for (int n=0;n<4;n++) acc[m][n] = (f32x4){0.f,0.f,0.f,0.f};

  // prologue
  {
    f32x4 a00 = *(const f32x4*)ap0, a01 = *(const f32x4*)(ap0+4);
    f32x4 a10 = *(const f32x4*)ap1, a11 = *(const f32x4*)(ap1+4);
    glds16(bp0, &Bs[0][bd0]);
    glds16(bp1, &Bs[0][bd1]);
    cvt8(&As[0][ad0], a00, a01);
    cvt8(&As[0][ad1], a10, a11);
  }
  __syncthreads();

  int cur = 0;
#pragma unroll 1
  for (int t = 0; t < 32; ++t) {
    const int nxt = cur ^ 1;
    f32x4 a00, a01, a10, a11;
    if (t < 31) {
      const int ko = (t+1)*32;
      a00 = *(const f32x4*)(ap0 + ko); a01 = *(const f32x4*)(ap0 + ko + 4);
      a10 = *(const f32x4*)(ap1 + ko); a11 = *(const f32x4*)(ap1 + ko + 4);
      glds16(bp0 + ko, &Bs[nxt][bd0]);
      glds16(bp1 + ko, &Bs[nxt][bd1]);
    }
    const __bf16* Asc = &As[cur][0];
    const __bf16* Bsc = &Bs[cur][0];
    bf16x8 af[4], bfv[4];
#pragma unroll
    for (int m=0;m<4;m++) {
      int row = wi*64 + m*16 + li;
      int ch  = lg ^ ((row >> 1) & 3);
      af[m] = *(const bf16x8*)(Asc + row*32 + ch*8);
    }
#pragma unroll
    for (int n=0;n<4;n++) {
      int row = wc*64 + n*16 + li;
      int ch  = lg ^ ((row >> 1) & 3);
      bfv[n] = *(const bf16x8*)(Bsc + row*32 + ch*8);
    }
#pragma unroll
    for (int m=0;m<4;m++)
#pragma unroll
      for (int n=0;n<4;n++)
        acc[m][n] = __builtin_amdgcn_mfma_f32_16x16x32_bf16(af[m], bfv[n], acc[m][n], 0, 0, 0);
    if (t < 31) {
      cvt8(&As[nxt][ad0], a00, a01);
      cvt8(&As[nxt][ad1], a10, a11);
    }
    __syncthreads();
    cur = nxt;
  }

  // epilogue -> bf16 partial plane
  unsigned short* pb = part + (size_t)kt*2097152u + (size_t)(b*1024 + i0)*256 + c0;
#pragma unroll
  for (int m=0;m<4;m++)
#pragma unroll
    for (int r=0;r<4;r++) {
      const int il = wi*64 + m*16 + lg*4 + r;
#pragma unroll
      for (int n=0;n<4;n++) {
        const int cl = wc*64 + n*16 + li;
        pb[(size_t)il*256 + cl] = bfbits(acc[m][n][r]);
      }
    }
}

// ---------------------------------------------------------------------------
// K3: out = relu(VW0 + sum_{kt} partial[kt]), 8 elems/thread
// ---------------------------------------------------------------------------
__global__ __launch_bounds__(256)
void k3_reduce(const unsigned short* __restrict__ part, const float* __restrict__ VW0,
               float* __restrict__ out)
{
  const size_t i8 = ((size_t)blockIdx.x*256 + threadIdx.x)*8;
  f32x4 s0 = *(const f32x4*)(VW0 + i8);
  f32x4 s1 = *(const f32x4*)(VW0 + i8 + 4);
#pragma unroll
  for (int p=0;p<4;p++) {
    u32x4 u = *(const u32x4*)(part + (size_t)p*2097152u + i8);
    s0[0] += __uint_as_float(u[0] << 16);  s0[1] += __uint_as_float(u[0] & 0xffff0000u);
    s0[2] += __uint_as_float(u[1] << 16);  s0[3] += __uint_as_float(u[1] & 0xffff0000u);
    s1[0] += __uint_as_float(u[2] << 16);  s1[1] += __uint_as_float(u[2] & 0xffff0000u);
    s1[2] += __uint_as_float(u[3] << 16);  s1[3] += __uint_as_float(u[3] & 0xffff0000u);
  }
#pragma unroll
  for (int e=0;e<4;e++){ s0[e] = fmaxf(s0[e],0.f); s1[e] = fmaxf(s1[e],0.f); }
  *(f32x4*)(out + i8)     = s0;
  *(f32x4*)(out + i8 + 4) = s1;
}

// ---------------------------------------------------------------------------
extern "C" void kernel_launch(void* const* d_in, const int* in_sizes, int n_in,
                              void* d_out, int out_size, void* d_ws, size_t ws_size,
                              hipStream_t stream) {
  const float* Vg = (const float*)d_in[0];   // (8,1024,256) f32
  const float* Ag = (const float*)d_in[1];   // (8,1024,1024,4) f32
  const float* Hg = (const float*)d_in[2];   // (5,256,256) f32
  float* out = (float*)d_out;                // (8,1024,256) f32

  // workspace layout: W2t bf16 16.78MB | VW0 f32 8.39MB | partials bf16 16.78MB
  if (ws_size < 41943040u) return;  // fail loudly (output stays wrong) rather than fault
  char* ws = (char*)d_ws;
  unsigned short* W2t  = (unsigned short*)(ws);
  float*          VW0  = (float*)(ws + 16777216u);
  unsigned short* part = (unsigned short*)(ws + 16777216u + 8388608u);

  k1_vw   <<<dim3(256),  dim3(512), 0, stream>>>(Vg, Hg, W2t, VW0);
  k2_gemm <<<dim3(512),  dim3(256), 0, stream>>>(Ag, W2t, part);
  k3_reduce<<<dim3(1024), dim3(256), 0, stream>>>(part, VW0, out);
}

// Round 3
// 58.030 us; speedup vs baseline: 1.1864x; 1.1864x over previous
//
#include <hip/hip_runtime.h>

// GraphConv: out[b,i,c] = relu( VW[b,0,i,c] + sum_{j,l} A[b,i,j,l] * VW[b,l+1,j,c] )
// VW[b,l,j,c] = sum_f V[b,j,f] h[l,c,f]
// K2 key fact: flattening A's (j,l) axes gives contiguous K=4096 with k=j*4+l.

typedef float          f32x4  __attribute__((ext_vector_type(4)));
typedef __bf16         bf16x8 __attribute__((ext_vector_type(8)));
typedef unsigned short u16x4  __attribute__((ext_vector_type(4)));
typedef unsigned int   u32x4  __attribute__((ext_vector_type(4)));

#define DEV __device__ __forceinline__

DEV void glds16(const void* g, void* l) {
  __builtin_amdgcn_global_load_lds((const __attribute__((address_space(1))) void*)g,
                                   (__attribute__((address_space(3))) void*)l,
                                   16, 0, 0);
}

DEV void cvt8(__bf16* d, f32x4 u, f32x4 v) {
  bf16x8 o;
  o[0]=(__bf16)u[0]; o[1]=(__bf16)u[1]; o[2]=(__bf16)u[2]; o[3]=(__bf16)u[3];
  o[4]=(__bf16)v[0]; o[5]=(__bf16)v[1]; o[6]=(__bf16)v[2]; o[7]=(__bf16)v[3];
  *(bf16x8*)d = o;
}

DEV bf16x8 cvt8r(f32x4 u, f32x4 v) {
  bf16x8 o;
  o[0]=(__bf16)u[0]; o[1]=(__bf16)u[1]; o[2]=(__bf16)u[2]; o[3]=(__bf16)u[3];
  o[4]=(__bf16)v[0]; o[5]=(__bf16)v[1]; o[6]=(__bf16)v[2]; o[7]=(__bf16)v[3];
  return o;
}

DEV unsigned short bfbits(float x) {
  return __builtin_bit_cast(unsigned short, (__bf16)x);
}

// ---------------------------------------------------------------------------
// K1: VW projection.  Per block: (b, j-tile 128, c-tile 64), all 5 l.
// M-axis = c (16-dim rows), N-axis = j, K = f (256, 4 steps of 64).
// Writes W2t[b][c][j*4 + (l-1)] bf16 (packed 4xl per store) and VW0[b][j][c] f32.
// ---------------------------------------------------------------------------
__global__ __launch_bounds__(512, 2)
void k1_vw(const float* __restrict__ Vg, const float* __restrict__ Hg,
           unsigned short* __restrict__ W2t, float* __restrict__ VW0)
{
  __shared__ __attribute__((aligned(16))) __bf16 Vs[2][128*64];  // 2 x 16 KB
  __shared__ __attribute__((aligned(16))) __bf16 Hs[2][320*64];  // 2 x 40 KB

  const int tid  = threadIdx.x;
  const int lane = tid & 63;
  const int wid  = tid >> 6;   // 0..7
  const int wj   = wid >> 1;   // 0..3 (j strips of 32)
  const int wc   = wid & 1;    // 0..1 (c strips of 32)
  const int li   = lane & 15;
  const int lg   = lane >> 4;

  const int bid = blockIdx.x;
  const int ct  = bid & 3;
  const int jt  = (bid >> 2) & 7;
  const int b   = bid >> 5;
  const int j0  = jt * 128;
  const int c0  = ct * 64;

  const float* sptr[7];
  int sdst[7];
#pragma unroll
  for (int r = 0; r < 2; ++r) {
    int n = r*512 + tid, row = n >> 3, q = n & 7;
    sptr[r] = Vg + (size_t)(b*1024 + j0 + row)*256 + q*8;
    sdst[r] = row*64 + ((q ^ (row & 7))*8);
  }
#pragma unroll
  for (int r = 0; r < 5; ++r) {
    int n = r*512 + tid, row = n >> 3, q = n & 7;
    int l = row >> 6, cl = row & 63;
    sptr[2+r] = Hg + (size_t)(l*256 + c0 + cl)*256 + q*8;
    sdst[2+r] = row*64 + ((q ^ (row & 7))*8);
  }

  f32x4 acc[5][2][2];
#pragma unroll
  for (int l=0;l<5;l++)
#pragma unroll
    for (int x=0;x<2;x++)
#pragma unroll
      for (int y=0;y<2;y++) acc[l][x][y] = (f32x4){0.f,0.f,0.f,0.f};

  {
    f32x4 sa[14];
#pragma unroll
    for (int i=0;i<7;i++) { sa[2*i] = *(const f32x4*)(sptr[i]); sa[2*i+1] = *(const f32x4*)(sptr[i]+4); }
#pragma unroll
    for (int i=0;i<7;i++) {
      __bf16* d = (i < 2) ? &Vs[0][sdst[i]] : &Hs[0][sdst[i]];
      cvt8(d, sa[2*i], sa[2*i+1]);
    }
  }
  __syncthreads();

  int cur = 0;
#pragma unroll 1
  for (int t = 0; t < 4; ++t) {
    const int nxt = cur ^ 1;
    f32x4 sa[14];
    if (t < 3) {
      const int ko = (t+1)*64;
#pragma unroll
      for (int i=0;i<7;i++) { sa[2*i] = *(const f32x4*)(sptr[i]+ko); sa[2*i+1] = *(const f32x4*)(sptr[i]+ko+4); }
    }
    const __bf16* Vsc = &Vs[cur][0];
    const __bf16* Hsc = &Hs[cur][0];
#pragma unroll
    for (int ks = 0; ks < 2; ++ks) {
      bf16x8 hf[10], vf[2];
#pragma unroll
      for (int l=0;l<5;l++)
#pragma unroll
        for (int cm=0;cm<2;cm++) {
          int row = l*64 + wc*32 + cm*16 + li;
          int ch  = (ks*4 + lg) ^ (row & 7);
          hf[l*2+cm] = *(const bf16x8*)(Hsc + row*64 + ch*8);
        }
#pragma unroll
      for (int jn=0;jn<2;jn++) {
        int row = wj*32 + jn*16 + li;
        int ch  = (ks*4 + lg) ^ (row & 7);
        vf[jn] = *(const bf16x8*)(Vsc + row*64 + ch*8);
      }
#pragma unroll
      for (int l=0;l<5;l++)
#pragma unroll
        for (int cm=0;cm<2;cm++)
#pragma unroll
          for (int jn=0;jn<2;jn++)
            acc[l][cm][jn] = __builtin_amdgcn_mfma_f32_16x16x32_bf16(
                hf[l*2+cm], vf[jn], acc[l][cm][jn], 0, 0, 0);
    }
    if (t < 3) {
#pragma unroll
      for (int i=0;i<7;i++) {
        __bf16* d = (i < 2) ? &Vs[nxt][sdst[i]] : &Hs[nxt][sdst[i]];
        cvt8(d, sa[2*i], sa[2*i+1]);
      }
    }
    __syncthreads();
    cur = nxt;
  }

#pragma unroll
  for (int cm=0;cm<2;cm++)
#pragma unroll
    for (int r=0;r<4;r++) {
      const int c = c0 + wc*32 + cm*16 + lg*4 + r;
#pragma unroll
      for (int jn=0;jn<2;jn++) {
        const int j = j0 + wj*32 + jn*16 + li;
        u16x4 pk;
        pk[0] = bfbits(acc[1][cm][jn][r]);
        pk[1] = bfbits(acc[2][cm][jn][r]);
        pk[2] = bfbits(acc[3][cm][jn][r]);
        pk[3] = bfbits(acc[4][cm][jn][r]);
        *(u16x4*)(W2t + (size_t)(b*256 + c)*4096 + (size_t)j*4) = pk;
        VW0[(size_t)(b*1024 + j)*256 + c] = acc[0][cm][jn][r];
      }
    }
}

// ---------------------------------------------------------------------------
// K2: partial[kt][b][i][c] = sum_{k in chunk} A[b][i][k] * W2t[b][c][k]
// tile 128x128, K-chunk 1024 (k-split 4), grid 512 = 2 blocks/CU.
// ALL staging via global_load_lds (A as raw f32, cvt at fragment read).
// 3-deep LDS pipeline, counted vmcnt(12) (never 0 in steady state),
// raw s_barrier. XCD swizzle: each XCD owns one batch b (A/W2t L2-resident).
// Swizzle invariant both sides: LDS chunk position q holds GLOBAL chunk q^s
// (s = row&7 for A / (row>>1)&3 for B); read of global chunk g is at g^s.
// ---------------------------------------------------------------------------
#define K2_WAITV12 asm volatile("s_waitcnt vmcnt(12)" ::: "memory")
#define K2_WAITV6  asm volatile("s_waitcnt vmcnt(6)"  ::: "memory")
#define K2_WAITV0  asm volatile("s_waitcnt vmcnt(0)"  ::: "memory")
#define K2_WAITL0  asm volatile("s_waitcnt lgkmcnt(0)" ::: "memory")
#define K2_BAR     __builtin_amdgcn_s_barrier()
#define K2_SB0     __builtin_amdgcn_sched_barrier(0)

#define K2_STAGE(buf, tt) do {                                   \
    const int _o = (tt)*32;                                      \
    glds16(asrc0 + _o, &As[buf][ad0]);                           \
    glds16(asrc1 + _o, &As[buf][ad1]);                           \
    glds16(asrc2 + _o, &As[buf][ad2]);                           \
    glds16(asrc3 + _o, &As[buf][ad3]);                           \
    glds16(bsrc0 + _o, &Bs[buf][bd0]);                           \
    glds16(bsrc1 + _o, &Bs[buf][bd1]);                           \
  } while (0)

#define K2_COMPUTE(buf) do {                                     \
    bf16x8 af[4], bfv[4];                                        \
    _Pragma("unroll")                                            \
    for (int m=0;m<4;m++) {                                      \
      int row = wi*64 + m*16 + li;                               \
      int p0  = (lg*2) ^ (row & 7);                              \
      f32x4 lo = *(const f32x4*)(&As[buf][row*32 + p0*4]);       \
      f32x4 hi = *(const f32x4*)(&As[buf][row*32 + (p0^1)*4]);   \
      af[m] = cvt8r(lo, hi);                                     \
    }                                                            \
    _Pragma("unroll")                                            \
    for (int n=0;n<4;n++) {                                      \
      int row = wc*64 + n*16 + li;                               \
      int p   = lg ^ ((row >> 1) & 3);                           \
      bfv[n] = *(const bf16x8*)(&Bs[buf][row*32 + p*8]);         \
    }                                                            \
    _Pragma("unroll")                                            \
    for (int m=0;m<4;m++)                                        \
      _Pragma("unroll")                                          \
      for (int n=0;n<4;n++)                                      \
        acc[m][n] = __builtin_amdgcn_mfma_f32_16x16x32_bf16(     \
            af[m], bfv[n], acc[m][n], 0, 0, 0);                  \
  } while (0)

__global__ __launch_bounds__(256, 2)
void k2_gemm(const float* __restrict__ Ag, const unsigned short* __restrict__ W2t,
             unsigned short* __restrict__ part)
{
  __shared__ __attribute__((aligned(16))) float  As[3][128*32];  // 3 x 16 KB
  __shared__ __attribute__((aligned(16))) __bf16 Bs[3][128*32];  // 3 x 8 KB

  const int tid  = threadIdx.x;
  const int lane = tid & 63;
  const int wid  = tid >> 6;   // 0..3
  const int wi   = wid >> 1;   // 0..1
  const int wc   = wid & 1;    // 0..1
  const int li   = lane & 15;
  const int lg   = lane >> 4;

  // XCD swizzle: physical p -> logical bid; each XCD (p&7) owns batch b=(p&7).
  const int p   = blockIdx.x;               // 512 blocks
  const int bid = (p & 7) * 64 + (p >> 3);
  const int ct  = bid & 1;
  const int kt  = (bid >> 1) & 3;
  const int it  = (bid >> 3) & 7;
  const int b   = bid >> 6;

  const int i0 = it*128, c0 = ct*128;
  const int k0 = kt*1024;

  // A staging sources: 4 chunks/thread. chunk n=r*256+tid: row=n>>3, q=n&7.
  // LDS linear dest chunk n holds global chunk q^(row&7) (pre-swizzled source).
  const float *asrc0, *asrc1, *asrc2, *asrc3;
  int ad0, ad1, ad2, ad3;
  {
    int n, row, q;
    n = tid;        row = n>>3; q = n&7;
    asrc0 = Ag + (size_t)(b*1024 + i0 + row)*4096 + k0 + ((q ^ (row&7))*4);  ad0 = n*4;
    n = 256 + tid;  row = n>>3; q = n&7;
    asrc1 = Ag + (size_t)(b*1024 + i0 + row)*4096 + k0 + ((q ^ (row&7))*4);  ad1 = n*4;
    n = 512 + tid;  row = n>>3; q = n&7;
    asrc2 = Ag + (size_t)(b*1024 + i0 + row)*4096 + k0 + ((q ^ (row&7))*4);  ad2 = n*4;
    n = 768 + tid;  row = n>>3; q = n&7;
    asrc3 = Ag + (size_t)(b*1024 + i0 + row)*4096 + k0 + ((q ^ (row&7))*4);  ad3 = n*4;
  }
  // B staging sources: 2 chunks/thread. chunk n=r*256+tid: row=n>>2, q=n&3.
  const unsigned short *bsrc0, *bsrc1;
  int bd0, bd1;
  {
    int n, row, q;
    n = tid;        row = n>>2; q = n&3;
    bsrc0 = W2t + (size_t)(b*256 + c0 + row)*4096 + k0 + ((q ^ ((row>>1)&3))*8);  bd0 = n*8;
    n = 256 + tid;  row = n>>2; q = n&3;
    bsrc1 = W2t + (size_t)(b*256 + c0 + row)*4096 + k0 + ((q ^ ((row>>1)&3))*8);  bd1 = n*8;
  }

  f32x4 acc[4][4];
#pragma unroll
  for (int m=0;m<4;m++)
#pragma unroll
    for (int n=0;n<4;n++) acc[m][n] = (f32x4){0.f,0.f,0.f,0.f};

  // prologue: stage k-steps 0 and 1
  K2_STAGE(0, 0);
  K2_STAGE(1, 1);

  int t = 0;
#pragma unroll 1
  for (int u = 0; u < 10; ++u) {
    K2_STAGE(2, t+2); K2_WAITV12; K2_BAR; K2_SB0;
    K2_COMPUTE(0);
    K2_WAITL0; K2_BAR; K2_SB0; ++t;

    K2_STAGE(0, t+2); K2_WAITV12; K2_BAR; K2_SB0;
    K2_COMPUTE(1);
    K2_WAITL0; K2_BAR; K2_SB0; ++t;

    K2_STAGE(1, t+2); K2_WAITV12; K2_BAR; K2_SB0;
    K2_COMPUTE(2);
    K2_WAITL0; K2_BAR; K2_SB0; ++t;
  }
  // t = 30: stages for t=30 (buf0) and t=31 (buf1) outstanding
  K2_WAITV6; K2_BAR; K2_SB0;
  K2_COMPUTE(0);
  K2_WAITL0; K2_BAR; K2_SB0;
  // t = 31
  K2_WAITV0; K2_BAR; K2_SB0;
  K2_COMPUTE(1);

  // epilogue -> bf16 partial plane
  unsigned short* pb = part + (size_t)kt*2097152u + (size_t)(b*1024 + i0)*256 + c0;
#pragma unroll
  for (int m=0;m<4;m++)
#pragma unroll
    for (int r=0;r<4;r++) {
      const int il = wi*64 + m*16 + lg*4 + r;
#pragma unroll
      for (int n=0;n<4;n++) {
        const int cl = wc*64 + n*16 + li;
        pb[(size_t)il*256 + cl] = bfbits(acc[m][n][r]);
      }
    }
}

// ---------------------------------------------------------------------------
// K3: out = relu(VW0 + sum_{kt} partial[kt]), 8 elems/thread
// ---------------------------------------------------------------------------
__global__ __launch_bounds__(256)
void k3_reduce(const unsigned short* __restrict__ part, const float* __restrict__ VW0,
               float* __restrict__ out)
{
  const size_t i8 = ((size_t)blockIdx.x*256 + threadIdx.x)*8;
  f32x4 s0 = *(const f32x4*)(VW0 + i8);
  f32x4 s1 = *(const f32x4*)(VW0 + i8 + 4);
#pragma unroll
  for (int p=0;p<4;p++) {
    u32x4 u = *(const u32x4*)(part + (size_t)p*2097152u + i8);
    s0[0] += __uint_as_float(u[0] << 16);  s0[1] += __uint_as_float(u[0] & 0xffff0000u);
    s0[2] += __uint_as_float(u[1] << 16);  s0[3] += __uint_as_float(u[1] & 0xffff0000u);
    s1[0] += __uint_as_float(u[2] << 16);  s1[1] += __uint_as_float(u[2] & 0xffff0000u);
    s1[2] += __uint_as_float(u[3] << 16);  s1[3] += __uint_as_float(u[3] & 0xffff0000u);
  }
#pragma unroll
  for (int e=0;e<4;e++){ s0[e] = fmaxf(s0[e],0.f); s1[e] = fmaxf(s1[e],0.f); }
  *(f32x4*)(out + i8)     = s0;
  *(f32x4*)(out + i8 + 4) = s1;
}

// ---------------------------------------------------------------------------
extern "C" void kernel_launch(void* const* d_in, const int* in_sizes, int n_in,
                              void* d_out, int out_size, void* d_ws, size_t ws_size,
                              hipStream_t stream) {
  const float* Vg = (const float*)d_in[0];   // (8,1024,256) f32
  const float* Ag = (const float*)d_in[1];   // (8,1024,1024,4) f32
  const float* Hg = (const float*)d_in[2];   // (5,256,256) f32
  float* out = (float*)d_out;                // (8,1024,256) f32

  if (ws_size < 41943040u) return;
  char* ws = (char*)d_ws;
  unsigned short* W2t  = (unsigned short*)(ws);
  float*          VW0  = (float*)(ws + 16777216u);
  unsigned short* part = (unsigned short*)(ws + 16777216u + 8388608u);

  k1_vw   <<<dim3(256),  dim3(512), 0, stream>>>(Vg, Hg, W2t, VW0);
  k2_gemm <<<dim3(512),  dim3(256), 0, stream>>>(Ag, W2t, part);
  k3_reduce<<<dim3(1024), dim3(256), 0, stream>>>(part, VW0, out);
}